// Round 1
// 636.275 us; speedup vs baseline: 1.1451x; 1.1451x over previous
//
#include <hip/hip_runtime.h>
#include <hip/hip_bf16.h>
#include <cstdint>

// ---------- types ----------
typedef __attribute__((ext_vector_type(4))) float f32x4;
typedef __attribute__((ext_vector_type(8))) short bf16x8;   // 8 bf16 = 4 VGPRs
typedef __attribute__((ext_vector_type(4))) short s16x4;
typedef __attribute__((ext_vector_type(8))) short s16x8;

// fp32 -> bf16 round-to-nearest-even (inputs are finite; no NaN path needed)
__device__ __forceinline__ short f2bf(float f) {
    union { float f; unsigned u; } v; v.f = f;
    unsigned r = v.u + 0x7FFFu + ((v.u >> 16) & 1u);
    return (short)(r >> 16);
}

// ---------- elementwise cast x: fp32 -> bf16, 8 elem/thread ----------
__global__ __launch_bounds__(256) void cast_bf16(const float* __restrict__ in,
                                                 short* __restrict__ out, long n) {
    long i = ((long)blockIdx.x * 256 + threadIdx.x) * 8;
    if (i + 7 < n) {
        float4 a = *(const float4*)(in + i);
        float4 b = *(const float4*)(in + i + 4);
        s16x8 o;
        o[0] = f2bf(a.x); o[1] = f2bf(a.y); o[2] = f2bf(a.z); o[3] = f2bf(a.w);
        o[4] = f2bf(b.x); o[5] = f2bf(b.y); o[6] = f2bf(b.z); o[7] = f2bf(b.w);
        *(s16x8*)(out + i) = o;                     // 16B store
    }
}

// ---------- transpose + cast: in fp32 [E][R][C] -> out bf16 [E][C][R] ----------
__global__ __launch_bounds__(256) void transpose_cast(const float* __restrict__ in,
                                                      short* __restrict__ out,
                                                      int R, int C) {
    __shared__ float t[64][65];                 // +1 pad
    const size_t eoff = (size_t)blockIdx.z * R * C;
    in  += eoff;
    out += eoff;
    const int c0 = blockIdx.x * 64, r0 = blockIdx.y * 64;
    const int tid = threadIdx.x;
    const int rr  = tid >> 4;                   // 0..15
    const int cc4 = (tid & 15) * 4;             // 0..60 step 4
    #pragma unroll
    for (int i = 0; i < 4; ++i) {
        const int row = i * 16 + rr;
        float4 v = *(const float4*)(in + (size_t)(r0 + row) * C + c0 + cc4);
        t[row][cc4 + 0] = v.x; t[row][cc4 + 1] = v.y;
        t[row][cc4 + 2] = v.z; t[row][cc4 + 3] = v.w;
    }
    __syncthreads();
    #pragma unroll
    for (int i = 0; i < 4; ++i) {
        const int oc = i * 16 + rr;             // C-index = output row
        s16x4 o;
        o[0] = f2bf(t[cc4 + 0][oc]);
        o[1] = f2bf(t[cc4 + 1][oc]);
        o[2] = f2bf(t[cc4 + 2][oc]);
        o[3] = f2bf(t[cc4 + 3][oc]);
        *(s16x4*)(out + (size_t)(c0 + oc) * R + r0 + cc4) = o;   // 8B store
    }
}

// ---------- pipelined 256x256 GEMM ----------
// C[e] = A[e] (MxK row-major) * Bt[e]^T (Bt is NxK row-major).
// BK=32, 4-slot LDS ring (A: 4x16KB, B: 4x16KB = 128 KiB), staging 3 K-tiles
// ahead with counted s_waitcnt vmcnt(8) (never 0 in steady state).
// 8 waves = 2(M) x 4(N); wave tile 128x64; 2 phases/K-tile, 16 MFMA each.
//
// LDS slot layout: [256 rows][4 chunks of 16B], chunk slot XOR-swizzled:
//   phys = q ^ ((r>>1)&3)  -> every 16-lane ds_read_b128 group is 2-way (free).
// global_load_lds writes linearly (wave base + lane*16B), so the swizzle is
// applied to the GLOBAL source address (rule 21: both-sides-or-neither).

#define FENCE() asm volatile("" ::: "memory")
#define BARRIER() do { FENCE(); __builtin_amdgcn_s_barrier(); FENCE(); } while (0)

__device__ __forceinline__ void stage2(const short* g0, const short* g1, short* l0) {
    // two global_load_lds of 16B/lane: lane i lands at l0 + i*16B (and +8KB)
    __builtin_amdgcn_global_load_lds(
        (const __attribute__((address_space(1))) void*)g0,
        (__attribute__((address_space(3))) void*)l0, 16, 0, 0);
    __builtin_amdgcn_global_load_lds(
        (const __attribute__((address_space(1))) void*)g1,
        (__attribute__((address_space(3))) void*)(l0 + 4096), 16, 0, 0);
}

template <int FUSE>
__global__ __launch_bounds__(512, 2) void gemm_bt(const short* __restrict__ A,
                                                  const short* __restrict__ Bt,
                                                  void* __restrict__ Cout,
                                                  int M, int N, int K) {
    __shared__ short lds[65536];               // 128 KiB: A slots [0,32768), B [32768,65536)
    const int tid  = threadIdx.x;
    const int lane = tid & 63;
    const int wave = tid >> 6;                 // 0..7
    const int wm   = wave >> 2;                // 0..1  (M half)
    const int wn   = wave & 3;                 // 0..3  (N quarter)

    // ---- block -> (expert, m0, n0) with XCD-chunk swizzle (total % 8 == 0) ----
    const int tilesM = M >> 8;
    const int perE   = tilesM * (N >> 8);      // == gridDim.x
    const int total  = gridDim.x * gridDim.z;
    int lin = blockIdx.z * gridDim.x + blockIdx.x;
    lin = (lin & 7) * (total >> 3) + (lin >> 3);
    const int e   = lin / perE;
    const int rem = lin - e * perE;
    const int m0  = (rem % tilesM) << 8;
    const int n0  = (rem / tilesM) << 8;

    const short* Ab = A  + (size_t)e * M * K + (size_t)m0 * K;
    const short* Bb = Bt + (size_t)e * N * K + (size_t)n0 * K;

    // ---- staging per-thread constants (A and B share row-stride K) ----
    size_t goff[2];
    #pragma unroll
    for (int i = 0; i < 2; ++i) {
        const int p  = i * 512 + tid;          // physical 16B chunk 0..1023
        const int r  = p >> 2;                 // row 0..255
        const int sp = p & 3;                  // physical chunk slot
        const int q  = sp ^ ((r >> 1) & 3);    // logical k-chunk (inverse swizzle)
        goff[i] = (size_t)r * K + q * 8;       // shorts
    }
    const int lwb = wave * 512;                // wave-uniform LDS base (shorts)

    // ---- fragment-read per-thread LDS offsets (shorts within a slot) ----
    const int lrow = lane & 15, lq = lane >> 4;
    int offA[8], offB[4];
    #pragma unroll
    for (int m = 0; m < 8; ++m) {
        const int r = wm * 128 + m * 16 + lrow;
        offA[m] = (r * 4 + (lq ^ ((r >> 1) & 3))) * 8;
    }
    #pragma unroll
    for (int n = 0; n < 4; ++n) {
        const int r = wn * 64 + n * 16 + lrow;
        offB[n] = (r * 4 + (lq ^ ((r >> 1) & 3))) * 8;
    }

    f32x4 acc[8][4] = {};
    const int nk = K >> 5;                     // K-tiles of 32 (nk >= 3 required)

    // ---- prologue: stage tiles 0,1,2 (12 loads/wave); need tile 0 landed ----
    #pragma unroll
    for (int t = 0; t < 3; ++t) {
        const size_t k0 = (size_t)t * 32;
        short* da = lds + (t & 3) * 8192 + lwb;
        short* db = lds + 32768 + (t & 3) * 8192 + lwb;
        stage2(Ab + k0 + goff[0], Ab + k0 + goff[1], da);
        stage2(Bb + k0 + goff[0], Bb + k0 + goff[1], db);
    }
    asm volatile("s_waitcnt vmcnt(8)" ::: "memory");   // oldest 4 (= tile 0) landed
    BARRIER();

    for (int t = 0; t < nk; ++t) {
        const short* As = lds + (t & 3) * 8192;
        const short* Bs = lds + 32768 + (t & 3) * 8192;
        bf16x8 a0[4], b0[4], a1[4];

        // ================= phase 0: Mfrags 0-3 x Nfrags 0-3 =================
        #pragma unroll
        for (int m = 0; m < 4; ++m) a0[m] = *(const bf16x8*)(As + offA[m]);
        #pragma unroll
        for (int n = 0; n < 4; ++n) b0[n] = *(const bf16x8*)(Bs + offB[n]);
        if (t + 3 < nk) {                       // stage A of tile t+3 (slot of t-1)
            const size_t k0 = (size_t)(t + 3) * 32;
            stage2(Ab + k0 + goff[0], Ab + k0 + goff[1],
                   lds + ((t + 3) & 3) * 8192 + lwb);
        }
        BARRIER();
        __builtin_amdgcn_s_setprio(1);
        #pragma unroll
        for (int m = 0; m < 4; ++m)
            #pragma unroll
            for (int n = 0; n < 4; ++n)
                acc[m][n] = __builtin_amdgcn_mfma_f32_16x16x32_bf16(
                    a0[m], b0[n], acc[m][n], 0, 0, 0);
        __builtin_amdgcn_s_setprio(0);
        BARRIER();

        // ================= phase 1: Mfrags 4-7 x Nfrags 0-3 =================
        #pragma unroll
        for (int m = 0; m < 4; ++m) a1[m] = *(const bf16x8*)(As + offA[4 + m]);
        if (t + 3 < nk) {                       // stage B of tile t+3
            const size_t k0 = (size_t)(t + 3) * 32;
            stage2(Bb + k0 + goff[0], Bb + k0 + goff[1],
                   lds + 32768 + ((t + 3) & 3) * 8192 + lwb);
        }
        // counted waits: guarantee tile t+1 fully landed before next phase's
        // reads (vmcnt BEFORE the barrier propagates per-wave guarantees).
        if (t < nk - 3)       asm volatile("s_waitcnt vmcnt(8)" ::: "memory");
        else if (t == nk - 3) asm volatile("s_waitcnt vmcnt(4)" ::: "memory");
        else if (t == nk - 2) asm volatile("s_waitcnt vmcnt(0)" ::: "memory");
        BARRIER();
        __builtin_amdgcn_s_setprio(1);
        #pragma unroll
        for (int m = 0; m < 4; ++m)
            #pragma unroll
            for (int n = 0; n < 4; ++n)
                acc[4 + m][n] = __builtin_amdgcn_mfma_f32_16x16x32_bf16(
                    a1[m], b0[n], acc[4 + m][n], 0, 0, 0);
        __builtin_amdgcn_s_setprio(0);
        BARRIER();
    }

    // ---- epilogue — C/D layout (m89/m91): col = lane&15, row = (lane>>4)*4+reg
    const int r0q = lq << 2;
    const int cL  = lane & 15;
    if (FUSE) {
        short* C = (short*)Cout + (size_t)e * M * N;
        #pragma unroll
        for (int m = 0; m < 8; ++m)
            #pragma unroll
            for (int n = 0; n < 4; ++n)
                #pragma unroll
                for (int rr = 0; rr < 4; ++rr) {
                    const int row = m0 + wm * 128 + m * 16 + r0q + rr;
                    const int col = n0 + wn * 64 + n * 16 + cL;
                    float v = acc[m][n][rr];
                    v = 0.5f * v * (1.0f + erff(v * 0.70710678118654752f));
                    C[(size_t)row * N + col] = f2bf(v);
                }
    } else {
        float* C = (float*)Cout + (size_t)e * M * N;
        #pragma unroll
        for (int m = 0; m < 8; ++m)
            #pragma unroll
            for (int n = 0; n < 4; ++n)
                #pragma unroll
                for (int rr = 0; rr < 4; ++rr) {
                    const int row = m0 + wm * 128 + m * 16 + r0q + rr;
                    const int col = n0 + wn * 64 + n * 16 + cL;
                    C[(size_t)row * N + col] = acc[m][n][rr];
                }
    }
}

// ---------- launch ----------
extern "C" void kernel_launch(void* const* d_in, const int* in_sizes, int n_in,
                              void* d_out, int out_size, void* d_ws, size_t ws_size,
                              hipStream_t stream) {
    constexpr int E = 8, Ct = 2048, H = 1024, I = 4096;   // G = 1

    const float* x  = (const float*)d_in[0];   // [1,E,Ct,H]
    const float* wi = (const float*)d_in[1];   // [E,H,I]
    const float* wo = (const float*)d_in[2];   // [E,I,H]
    float* out = (float*)d_out;                // [1,E,Ct,H] fp32

    char* ws = (char*)d_ws;
    // ws layout (bytes): xb 32MiB | wiT 64MiB | woT 64MiB | h 128MiB = 288MiB
    short* xb  = (short*)(ws);
    short* wiT = (short*)(ws + (size_t)33554432);
    short* woT = (short*)(ws + (size_t)100663296);
    short* h   = (short*)(ws + (size_t)167772160);

    // 1) x fp32 -> bf16 (layout unchanged: [E][Ct][H] row-major)
    {
        long n = (long)E * Ct * H;             // 16,777,216
        cast_bf16<<<dim3((unsigned)(n / 2048)), dim3(256), 0, stream>>>(x, xb, n);
    }
    // 2) wi [E][H][I] -> wiT [E][I][H] bf16
    transpose_cast<<<dim3(I / 64, H / 64, E), dim3(256), 0, stream>>>(wi, wiT, H, I);
    // 3) wo [E][I][H] -> woT [E][H][I] bf16
    transpose_cast<<<dim3(H / 64, I / 64, E), dim3(256), 0, stream>>>(wo, woT, I, H);

    // 4) h = gelu(x @ wi):  M=Ct, N=I, K=H ; A=xb, Bt=wiT (NxK) ; bf16 out
    //    grid.x = tilesM*tilesN = 8*16 = 128 ; total 1024 (%8==0)
    gemm_bt<1><<<dim3(128, 1, E), dim3(512), 0, stream>>>(xb, wiT, (void*)h, Ct, I, H);

    // 5) out = h @ wo:      M=Ct, N=H, K=I ; A=h,  Bt=woT (NxK) ; fp32 out
    //    grid.x = 8*4 = 32 ; total 256 (%8==0)
    gemm_bt<0><<<dim3(32, 1, E), dim3(512), 0, stream>>>(h, woT, (void*)out, Ct, H, I);
}

// Round 3
// 614.266 us; speedup vs baseline: 1.1861x; 1.0358x over previous
//
#include <hip/hip_runtime.h>
#include <hip/hip_bf16.h>
#include <cstdint>

// ---------- types ----------
typedef __attribute__((ext_vector_type(4))) float f32x4;
typedef __attribute__((ext_vector_type(8))) short bf16x8;   // 8 bf16 = 4 VGPRs
typedef __attribute__((ext_vector_type(4))) short s16x4;
typedef __attribute__((ext_vector_type(8))) short s16x8;

// fp32 -> bf16 round-to-nearest-even (inputs are finite; no NaN path needed)
__device__ __forceinline__ short f2bf(float f) {
    union { float f; unsigned u; } v; v.f = f;
    unsigned r = v.u + 0x7FFFu + ((v.u >> 16) & 1u);
    return (short)(r >> 16);
}

// ---------- elementwise cast x: fp32 -> bf16, 8 elem/thread ----------
__global__ __launch_bounds__(256) void cast_bf16(const float* __restrict__ in,
                                                 short* __restrict__ out, long n) {
    long i = ((long)blockIdx.x * 256 + threadIdx.x) * 8;
    if (i + 7 < n) {
        float4 a = *(const float4*)(in + i);
        float4 b = *(const float4*)(in + i + 4);
        s16x8 o;
        o[0] = f2bf(a.x); o[1] = f2bf(a.y); o[2] = f2bf(a.z); o[3] = f2bf(a.w);
        o[4] = f2bf(b.x); o[5] = f2bf(b.y); o[6] = f2bf(b.z); o[7] = f2bf(b.w);
        *(s16x8*)(out + i) = o;                     // 16B store
    }
}

// ---------- transpose + cast: in fp32 [E][R][C] -> out bf16 [E][C][R] ----------
__global__ __launch_bounds__(256) void transpose_cast(const float* __restrict__ in,
                                                      short* __restrict__ out,
                                                      int R, int C) {
    __shared__ float t[64][65];                 // +1 pad
    const size_t eoff = (size_t)blockIdx.z * R * C;
    in  += eoff;
    out += eoff;
    const int c0 = blockIdx.x * 64, r0 = blockIdx.y * 64;
    const int tid = threadIdx.x;
    const int rr  = tid >> 4;                   // 0..15
    const int cc4 = (tid & 15) * 4;             // 0..60 step 4
    #pragma unroll
    for (int i = 0; i < 4; ++i) {
        const int row = i * 16 + rr;
        float4 v = *(const float4*)(in + (size_t)(r0 + row) * C + c0 + cc4);
        t[row][cc4 + 0] = v.x; t[row][cc4 + 1] = v.y;
        t[row][cc4 + 2] = v.z; t[row][cc4 + 3] = v.w;
    }
    __syncthreads();
    #pragma unroll
    for (int i = 0; i < 4; ++i) {
        const int oc = i * 16 + rr;             // C-index = output row
        s16x4 o;
        o[0] = f2bf(t[cc4 + 0][oc]);
        o[1] = f2bf(t[cc4 + 1][oc]);
        o[2] = f2bf(t[cc4 + 2][oc]);
        o[3] = f2bf(t[cc4 + 3][oc]);
        *(s16x4*)(out + (size_t)(c0 + oc) * R + r0 + cc4) = o;   // 8B store
    }
}

// ---------- 256x256 8-phase GEMM, counted-vmcnt pipeline ----------
// C[e] = A[e] (MxK row-major) * Bt[e]^T (Bt is NxK row-major).
// BK=64, 2-buffer LDS (2 x 64 KiB). Buffer regions (shorts): A0 @0, A1 @8192,
// B0 @16384, B1 @24576 (each 128 rows x 64 k = 16 KiB).
// Per K-tile: 4 phases (quadrants of each wave's 128x64 tile), 16 MFMA each;
// fragment reuse -> ds_reads/phase = 12/4/8/0.
//
// Region deaths within tile t (static wave halves wm/wn):
//   B0,B1 last read at p1;  A0,A1 last read at p2.
// Staging schedule (proved safe: every write is barrier-separated from the
// region's last readers; one vmcnt(6) per tile leaves exactly the 3 newest
// halves in flight and guarantees ALL of tile t+1 landed before its p0):
//   p0: stage A1(t+1) -> other buffer (tile t-1 data, dead)
//   p2: stage B0(t+2) -> current buffer (B0 died at p1)
//   p3: stage B1(t+2), A0(t+2) -> current buffer (died p1/p2); vmcnt(6)
// Tail: vmcnt(0) only at t = nk-2 (semantically forced; loads are old).
//
// LDS swizzle: row of 64 bf16 = 8 chunks of 16B; phys = q ^ (row&7) -> every
// 16-lane ds_read_b128 group is 2-way (free, m136). global_load_lds writes
// linearly, so the inverse swizzle is applied on the GLOBAL source (rule 21).

#define FENCE() asm volatile("" ::: "memory")
#define BARRIER() do { FENCE(); __builtin_amdgcn_s_barrier(); FENCE(); } while (0)

__device__ __forceinline__ void stage_half(const short* __restrict__ g,
                                           short* l, const size_t* goff) {
    __builtin_amdgcn_global_load_lds(
        (const __attribute__((address_space(1))) void*)(g + goff[0]),
        (__attribute__((address_space(3))) void*)l, 16, 0, 0);
    __builtin_amdgcn_global_load_lds(
        (const __attribute__((address_space(1))) void*)(g + goff[1]),
        (__attribute__((address_space(3))) void*)(l + 4096), 16, 0, 0);
}

template <int FUSE>
__global__ __launch_bounds__(512, 2) void gemm_bt(const short* __restrict__ A,
                                                  const short* __restrict__ Bt,
                                                  void* __restrict__ Cout,
                                                  int M, int N, int K) {
    __shared__ short lds[65536];               // 128 KiB
    const int tid  = threadIdx.x;
    const int lane = tid & 63;
    const int wave = tid >> 6;                 // 0..7
    const int wm   = wave >> 2;                // 0..1  (A half)
    const int wn   = wave & 3;                 // 0..3  (B quarter; half = wn>>1)

    // ---- block -> (expert, m0, n0) with XCD-chunk swizzle (total % 8 == 0) ----
    const int tilesM = M >> 8;
    const int perE   = tilesM * (N >> 8);      // == gridDim.x
    const int total  = gridDim.x * gridDim.z;
    int lin = blockIdx.z * gridDim.x + blockIdx.x;
    lin = (lin & 7) * (total >> 3) + (lin >> 3);
    const int e   = lin / perE;
    const int rem = lin - e * perE;
    const int m0  = (rem % tilesM) << 8;
    const int n0  = (rem / tilesM) << 8;

    const short* Ab = A  + (size_t)e * M * K + (size_t)m0 * K;
    const short* Bb = Bt + (size_t)e * N * K + (size_t)n0 * K;
    const size_t hK = (size_t)128 * K;         // half-tile row stride (shorts)

    // ---- staging per-thread global offsets (inverse-swizzled source) ----
    size_t goff[2];
    #pragma unroll
    for (int i = 0; i < 2; ++i) {
        const int p  = i * 512 + tid;          // physical 16B chunk 0..1023
        const int r  = p >> 3;                 // row 0..127
        const int sp = p & 7;                  // physical chunk slot
        goff[i] = (size_t)r * K + (size_t)((sp ^ (r & 7)) << 3);   // shorts
    }
    const int lwb = wave * 512;                // wave-uniform LDS base (shorts)

    // ---- fragment-read LDS offsets (shorts, relative to buffer base), s=0 ----
    // s=1 fragment = offset ^ 32 (flips chunk bit2 -> logical k-chunk +4)
    const int lrow = lane & 15, lq = lane >> 4;
    int offA[8], offB[4];
    #pragma unroll
    for (int m = 0; m < 8; ++m) {
        const int rh = m * 16 + lrow;          // row within wave's A half
        offA[m] = wm * 8192 + rh * 64 + ((lq ^ (rh & 7)) << 3);
    }
    #pragma unroll
    for (int n = 0; n < 4; ++n) {
        const int row = wn * 64 + n * 16 + lrow;   // B row 0..255
        const int h = row >> 7, rh = row & 127;
        offB[n] = 16384 + h * 8192 + rh * 64 + ((lq ^ (rh & 7)) << 3);
    }

    f32x4 acc[8][4] = {};
    const int nk = K >> 6;                     // K-tiles of 64 (nk >= 2 here)

    // ---- prologue: tile 0 complete + tile 1's B0,B1,A0 in flight ----
    stage_half(Ab,      lds +     0 + lwb, goff);   // A0(0)
    stage_half(Ab + hK, lds +  8192 + lwb, goff);   // A1(0)
    stage_half(Bb,      lds + 16384 + lwb, goff);   // B0(0)
    stage_half(Bb + hK, lds + 24576 + lwb, goff);   // B1(0)
    if (nk > 1) {
        const short* A1p = Ab + 64;
        const short* B1p = Bb + 64;
        stage_half(B1p,      lds + 32768 + 16384 + lwb, goff);  // B0(1)
        stage_half(B1p + hK, lds + 32768 + 24576 + lwb, goff);  // B1(1)
        stage_half(A1p,      lds + 32768 +     0 + lwb, goff);  // A0(1)
        asm volatile("s_waitcnt vmcnt(6)" ::: "memory");        // tile 0 landed
    } else {
        asm volatile("s_waitcnt vmcnt(0)" ::: "memory");
    }
    BARRIER();

    bf16x8 Af[4][2], Bf0[2][2], Bf1[2][2];

    for (int t = 0; t < nk; ++t) {
        const int sl  = (t & 1) << 15;         // current buffer (shorts)
        const int slN = ((t + 1) & 1) << 15;   // next-tile buffer
        const short* S = lds + sl;
        const short* An1 = Ab + (size_t)(t + 1) * 64;
        const short* An2 = Ab + (size_t)(t + 2) * 64;
        const short* Bn2 = Bb + (size_t)(t + 2) * 64;

        // ===== p0: 12 reads; MFMA acc[0..3][0..1]; stage A1(t+1) -> other buf
        #pragma unroll
        for (int i = 0; i < 4; ++i) {
            const int o = offA[i];
            Af[i][0] = *(const bf16x8*)(S + o);
            Af[i][1] = *(const bf16x8*)(S + (o ^ 32));
        }
        #pragma unroll
        for (int j = 0; j < 2; ++j) {
            const int o = offB[j];
            Bf0[j][0] = *(const bf16x8*)(S + o);
            Bf0[j][1] = *(const bf16x8*)(S + (o ^ 32));
        }
        if (t + 1 < nk) stage_half(An1 + hK, lds + slN + 8192 + lwb, goff);
        BARRIER();
        __builtin_amdgcn_s_setprio(1);
        #pragma unroll
        for (int s = 0; s < 2; ++s)
            #pragma unroll
            for (int i = 0; i < 4; ++i)
                #pragma unroll
                for (int j = 0; j < 2; ++j)
                    acc[i][j] = __builtin_amdgcn_mfma_f32_16x16x32_bf16(
                        Af[i][s], Bf0[j][s], acc[i][j], 0, 0, 0);
        __builtin_amdgcn_s_setprio(0);
        BARRIER();

        // ===== p1: 4 reads; MFMA acc[0..3][2..3]; no staging
        #pragma unroll
        for (int j = 0; j < 2; ++j) {
            const int o = offB[2 + j];
            Bf1[j][0] = *(const bf16x8*)(S + o);
            Bf1[j][1] = *(const bf16x8*)(S + (o ^ 32));
        }
        BARRIER();
        __builtin_amdgcn_s_setprio(1);
        #pragma unroll
        for (int s = 0; s < 2; ++s)
            #pragma unroll
            for (int i = 0; i < 4; ++i)
                #pragma unroll
                for (int j = 0; j < 2; ++j)
                    acc[i][2 + j] = __builtin_amdgcn_mfma_f32_16x16x32_bf16(
                        Af[i][s], Bf1[j][s], acc[i][2 + j], 0, 0, 0);
        __builtin_amdgcn_s_setprio(0);
        BARRIER();

        // ===== p2: 8 reads; MFMA acc[4..7][2..3]; stage B0(t+2) -> cur buf
        #pragma unroll
        for (int i = 0; i < 4; ++i) {
            const int o = offA[4 + i];
            Af[i][0] = *(const bf16x8*)(S + o);
            Af[i][1] = *(const bf16x8*)(S + (o ^ 32));
        }
        if (t + 2 < nk) stage_half(Bn2, lds + sl + 16384 + lwb, goff);
        BARRIER();
        __builtin_amdgcn_s_setprio(1);
        #pragma unroll
        for (int s = 0; s < 2; ++s)
            #pragma unroll
            for (int i = 0; i < 4; ++i)
                #pragma unroll
                for (int j = 0; j < 2; ++j)
                    acc[4 + i][2 + j] = __builtin_amdgcn_mfma_f32_16x16x32_bf16(
                        Af[i][s], Bf1[j][s], acc[4 + i][2 + j], 0, 0, 0);
        __builtin_amdgcn_s_setprio(0);
        BARRIER();

        // ===== p3: 0 reads; stage B1(t+2), A0(t+2) -> cur buf; counted wait
        if (t + 2 < nk) {
            stage_half(Bn2 + hK, lds + sl + 24576 + lwb, goff);
            stage_half(An2,      lds + sl +     0 + lwb, goff);
            asm volatile("s_waitcnt vmcnt(6)" ::: "memory");   // tile t+1 landed
        } else {
            asm volatile("s_waitcnt vmcnt(0)" ::: "memory");   // drain (tail only)
        }
        BARRIER();
        __builtin_amdgcn_s_setprio(1);
        #pragma unroll
        for (int s = 0; s < 2; ++s)
            #pragma unroll
            for (int i = 0; i < 4; ++i)
                #pragma unroll
                for (int j = 0; j < 2; ++j)
                    acc[4 + i][j] = __builtin_amdgcn_mfma_f32_16x16x32_bf16(
                        Af[i][s], Bf0[j][s], acc[4 + i][j], 0, 0, 0);
        __builtin_amdgcn_s_setprio(0);
        BARRIER();
    }

    // ---- epilogue — C/D layout (m89/m91): col = lane&15, row = (lane>>4)*4+reg
    const int r0q = lq << 2;
    const int cL  = lane & 15;
    if (FUSE) {
        short* C = (short*)Cout + (size_t)e * M * N;
        #pragma unroll
        for (int m = 0; m < 8; ++m)
            #pragma unroll
            for (int n = 0; n < 4; ++n)
                #pragma unroll
                for (int rr = 0; rr < 4; ++rr) {
                    const int row = m0 + wm * 128 + m * 16 + r0q + rr;
                    const int col = n0 + wn * 64 + n * 16 + cL;
                    float v = acc[m][n][rr];
                    v = 0.5f * v * (1.0f + erff(v * 0.70710678118654752f));
                    C[(size_t)row * N + col] = f2bf(v);
                }
    } else {
        float* C = (float*)Cout + (size_t)e * M * N;
        #pragma unroll
        for (int m = 0; m < 8; ++m)
            #pragma unroll
            for (int n = 0; n < 4; ++n)
                #pragma unroll
                for (int rr = 0; rr < 4; ++rr) {
                    const int row = m0 + wm * 128 + m * 16 + r0q + rr;
                    const int col = n0 + wn * 64 + n * 16 + cL;
                    C[(size_t)row * N + col] = acc[m][n][rr];
                }
    }
}

// ---------- launch ----------
extern "C" void kernel_launch(void* const* d_in, const int* in_sizes, int n_in,
                              void* d_out, int out_size, void* d_ws, size_t ws_size,
                              hipStream_t stream) {
    constexpr int E = 8, Ct = 2048, H = 1024, I = 4096;   // G = 1

    const float* x  = (const float*)d_in[0];   // [1,E,Ct,H]
    const float* wi = (const float*)d_in[1];   // [E,H,I]
    const float* wo = (const float*)d_in[2];   // [E,I,H]
    float* out = (float*)d_out;                // [1,E,Ct,H] fp32

    char* ws = (char*)d_ws;
    // ws layout (bytes): xb 32MiB | wiT 64MiB | woT 64MiB | h 128MiB = 288MiB
    short* xb  = (short*)(ws);
    short* wiT = (short*)(ws + (size_t)33554432);
    short* woT = (short*)(ws + (size_t)100663296);
    short* h   = (short*)(ws + (size_t)167772160);

    // 1) x fp32 -> bf16 (layout unchanged: [E][Ct][H] row-major)
    {
        long n = (long)E * Ct * H;             // 16,777,216
        cast_bf16<<<dim3((unsigned)(n / 2048)), dim3(256), 0, stream>>>(x, xb, n);
    }
    // 2) wi [E][H][I] -> wiT [E][I][H] bf16
    transpose_cast<<<dim3(I / 64, H / 64, E), dim3(256), 0, stream>>>(wi, wiT, H, I);
    // 3) wo [E][I][H] -> woT [E][H][I] bf16
    transpose_cast<<<dim3(H / 64, I / 64, E), dim3(256), 0, stream>>>(wo, woT, I, H);

    // 4) h = gelu(x @ wi):  M=Ct, N=I, K=H ; A=xb, Bt=wiT (NxK) ; bf16 out
    gemm_bt<1><<<dim3(128, 1, E), dim3(512), 0, stream>>>(xb, wiT, (void*)h, Ct, I, H);

    // 5) out = h @ wo:      M=Ct, N=H, K=I ; A=h,  Bt=woT (NxK) ; fp32 out
    gemm_bt<0><<<dim3(32, 1, E), dim3(512), 0, stream>>>(h, woT, (void*)out, Ct, H, I);
}